// Round 5
// baseline (867.742 us; speedup 1.0000x reference)
//
#include <hip/hip_runtime.h>
#include <math.h>

#define T_STEPS 256
#define BATCH   4096
#define HID     64
#define MW      128
#define DOUT    8
#define RPB     16    // rows per block -> grid = 256 = 1 block/CU (grid-limited)
#define NTH     1024  // 16 waves -> 4 waves/SIMD; ph1/2: (mlp 2) x (oct 8)
#define AS      72    // Ain/zb row stride in halfs (144B)
#define HS      136   // h1/h2 row stride in halfs (272B)

typedef _Float16 half8 __attribute__((ext_vector_type(8)));
typedef float    f32x4 __attribute__((ext_vector_type(4)));

__device__ __forceinline__ float fast_rcp(float x) { return __builtin_amdgcn_rcpf(x); }
// plain silu: the 0.909 lipswish factor is folded into the NEXT layer's f16 weights
__device__ __forceinline__ float silu(float x) {
    float e = __expf(-x);
    return x * fast_rcp(1.0f + e);
}
__device__ __forceinline__ float fast_tanh(float x) {
    float e = __expf(2.0f * x);
    return 1.0f - 2.0f * fast_rcp(e + 1.0f);
}

#define MFMA(a, b, c) __builtin_amdgcn_mfma_f32_16x16x32_f16((a), (b), (c), 0, 0, 0)

// MFMA 16x16x32 layout (gfx950, guide-verified):
//   A[m][k]: m = lane&15 (batch row), k = (lane>>4)*8 + j
//   B[k][n]: n = lane&15 (out-neuron), k = (lane>>4)*8 + j
//   C/D   : col n = lane&15 (out-neuron), row m = (lane>>4)*4 + reg (batch row)
// Phase 3: the lane producing f,g for (rows quad*4+i, col (wid&3)*16+l15) also
// owns z/zhat for those elements -> update needs no cross-lane/LDS transpose.

__global__ __launch_bounds__(NTH, 1)   // grid = 1 block/CU: VGPRs free to 128
void sde_kernel(const float* __restrict__ ts,
                const float* __restrict__ dW,
                const float* __restrict__ dW0, const float* __restrict__ db0,
                const float* __restrict__ dW1, const float* __restrict__ db1,
                const float* __restrict__ dWo, const float* __restrict__ dbo,
                const float* __restrict__ gW0, const float* __restrict__ gb0,
                const float* __restrict__ gW1, const float* __restrict__ gb1,
                const float* __restrict__ gWo, const float* __restrict__ gbo,
                const float* __restrict__ rW,  const float* __restrict__ rb,
                float* __restrict__ out)
{
    __shared__ _Float16 Ain_hi[RPB][AS];   // L1 input (t-folded), hi part
    __shared__ _Float16 Ain_lo[RPB][AS];   // L1 input, lo part (fp32-exact split)
    __shared__ _Float16 h1b[2][RPB][HS];   // layer-1 out per mlp (plain silu)
    __shared__ _Float16 h2b[2][RPB][HS];   // layer-2 out per mlp (plain silu)
    __shared__ _Float16 zb[2][RPB][AS];    // z stash (f16) for MFMA readout
    __shared__ float    bias1t[2 * MW];    // per-step L1 bias incl. t * W0row0
    __shared__ float    tsS[T_STEPS];

    const int tid  = threadIdx.x;
    const int lane = tid & 63;
    const int wid  = tid >> 6;     // 0..15
    const int l15  = lane & 15;
    const int quad = lane >> 4;
    const int mlp  = wid >> 3;     // ph1/2 role: 0 = drift, 1 = diff
    const int oct  = wid & 7;      // 16-col slice of the 128 neurons
    const int cb   = oct * 16;     // col base
    const int rowbase = blockIdx.x * RPB;

    for (int i = tid; i < T_STEPS; i += NTH) tsS[i] = ts[i];

    const float t0   = ts[0];
    const float dt   = ts[1] - t0;
    const float sqdt = sqrtf(dt);

    // ---------------- static weight fragments (B-operand) ----------------
    const float* W0 = mlp ? gW0 : dW0;   // (65,128); row 0 = t weights
    const float* W1 = mlp ? gW1 : dW1;   // (128,128)

    half8 bw1[2], bw2[4];
    #pragma unroll
    for (int kt = 0; kt < 2; ++kt) {
        half8 v;
        #pragma unroll
        for (int j = 0; j < 8; ++j) {
            const int k = kt * 32 + quad * 8 + j;
            v[j] = (_Float16)W0[(1 + k) * MW + cb + l15];
        }
        bw1[kt] = v;
    }
    #pragma unroll
    for (int kt = 0; kt < 4; ++kt) {
        half8 v;
        #pragma unroll
        for (int j = 0; j < 8; ++j) {
            const int k = kt * 32 + quad * 8 + j;
            v[j] = (_Float16)(0.909f * W1[k * MW + cb + l15]);   // 0.909 folded
        }
        bw2[kt] = v;
    }

    const float b2v = (mlp ? gb1 : db1)[cb + l15];

    // ---------------- phase-3 state (waves 0-3) ----------------
    // state wave w owns cols ucol = w*16+l15, rows quad*4+i.
    const int ucol = (wid & 3) * 16 + l15;
    const int urow = quad * 4;

    half8 bw3f[4], bw3g[4];          // 0.909-folded Wo fragments (wid<4 only)
    float b3f = 0.0f, b3g = 0.0f;
    float z[4], zh[4], fold[4], gold[4], dwr[4], dn[4];
    if (wid < 4) {
        #pragma unroll
        for (int kt = 0; kt < 4; ++kt) {
            half8 vf, vg;
            #pragma unroll
            for (int j = 0; j < 8; ++j) {
                const int k = kt * 32 + quad * 8 + j;
                vf[j] = (_Float16)(0.909f * dWo[k * HID + ucol]);
                vg[j] = (_Float16)(0.909f * gWo[k * HID + ucol]);
            }
            bw3f[kt] = vf;
            bw3g[kt] = vg;
        }
        b3f = dbo[ucol];
        b3g = gbo[ucol];
        #pragma unroll
        for (int i = 0; i < 4; ++i) {
            z[i] = 1.0f; zh[i] = 1.0f; dwr[i] = 0.0f;
            dn[i] = dW[(size_t)(rowbase + urow + i) * HID + ucol];   // dW[0]
            Ain_hi[urow + i][ucol] = (_Float16)1.0f;                 // x0 = ones
            Ain_lo[urow + i][ucol] = (_Float16)0.0f;
        }
    }

    // readout fragments (wave 4)
    half8 brd[2];
    float rbv = 0.0f;
    int   ocol = 0;
    if (wid == 4) {
        #pragma unroll
        for (int kt = 0; kt < 2; ++kt) {
            half8 v;
            #pragma unroll
            for (int j = 0; j < 8; ++j) {
                const int k = kt * 32 + quad * 8 + j;
                v[j] = (l15 < 8) ? (_Float16)rW[k * DOUT + l15] : (_Float16)0.0f;
            }
            brd[kt] = v;
        }
        rbv  = (l15 < 8) ? rb[l15] : 0.0f;
        ocol = (l15 == 8) ? 0 : (l15 + 1);
    }

    // t-folded L1 bias owned by waves 12..15 (256 threads cover 2*MW slots)
    float b0s = 0.0f, w0s = 0.0f;
    if (tid >= 768) {
        const int idx = tid - 768;
        b0s = (idx < MW ? db0 : gb0)[idx & (MW - 1)];
        w0s = (idx < MW ? dW0 : gW0)[idx & (MW - 1)];  // W0 row 0
        bias1t[idx] = b0s + t0 * w0s;
    }
    __syncthreads();

    const int koff = quad * 8;

    for (int n = 1; n <= T_STEPS; ++n) {
        // ================= Phase 1: Layer 1, 64 -> 128 (split-A hi/lo) ========
        {
            half8 ah[2], al[2];
            #pragma unroll
            for (int kt = 0; kt < 2; ++kt) {
                ah[kt] = *(const half8*)&Ain_hi[l15][kt * 32 + koff];
                al[kt] = *(const half8*)&Ain_lo[l15][kt * 32 + koff];
            }
            const float b = bias1t[mlp * MW + cb + l15];
            f32x4 acc = (f32x4){b, b, b, b};
            #pragma unroll
            for (int kt = 0; kt < 2; ++kt) {
                acc = MFMA(ah[kt], bw1[kt], acc);
                acc = MFMA(al[kt], bw1[kt], acc);
            }
            #pragma unroll
            for (int i2 = 0; i2 < 4; ++i2)
                h1b[mlp][quad * 4 + i2][cb + l15] = (_Float16)silu(acc[i2]);
        }
        __syncthreads();

        // ================= Phase 2: Layer 2, 128 -> 128 =================
        {
            half8 a[4];
            #pragma unroll
            for (int kt = 0; kt < 4; ++kt)
                a[kt] = *(const half8*)&h1b[mlp][l15][kt * 32 + koff];
            f32x4 acc = (f32x4){b2v, b2v, b2v, b2v};
            #pragma unroll
            for (int kt = 0; kt < 4; ++kt)
                acc = MFMA(a[kt], bw2[kt], acc);
            #pragma unroll
            for (int i2 = 0; i2 < 4; ++i2)
                h2b[mlp][quad * 4 + i2][cb + l15] = (_Float16)silu(acc[i2]);
        }
        __syncthreads();

        // ===== Phase 3: L3 f&g (waves 0-3, in-register update);
        //                readout (wave 4); bias refresh (waves 12-15) =====
        if (wid < 4) {
            half8 a[4];
            #pragma unroll
            for (int kt = 0; kt < 4; ++kt)
                a[kt] = *(const half8*)&h2b[0][l15][kt * 32 + koff];
            f32x4 accF = (f32x4){b3f, b3f, b3f, b3f};
            #pragma unroll
            for (int kt = 0; kt < 4; ++kt)
                accF = MFMA(a[kt], bw3f[kt], accF);
            #pragma unroll
            for (int kt = 0; kt < 4; ++kt)
                a[kt] = *(const half8*)&h2b[1][l15][kt * 32 + koff];
            f32x4 accG = (f32x4){b3g, b3g, b3g, b3g};
            #pragma unroll
            for (int kt = 0; kt < 4; ++kt)
                accG = MFMA(a[kt], bw3g[kt], accG);

            const int p = n & 1;
            const int np = (n < T_STEPS - 2) ? n : (T_STEPS - 2);
            #pragma unroll
            for (int i = 0; i < 4; ++i) {
                const float fn = fast_tanh(accF[i]);
                const float gn = fast_tanh(accG[i]);
                if (n > 1)
                    z[i] += 0.5f * (fold[i] + fn) * dt + 0.5f * (gold[i] + gn) * dwr[i];
                zb[p][urow + i][ucol] = (_Float16)z[i];
                if (n < T_STEPS) {
                    dwr[i] = dn[i] * sqdt;
                    dn[i]  = dW[(size_t)np * (BATCH * HID)
                                + (size_t)(rowbase + urow + i) * HID + ucol];
                    zh[i]  = 2.0f * z[i] - zh[i] + fn * dt + gn * dwr[i];
                    const _Float16 hi = (_Float16)zh[i];
                    Ain_hi[urow + i][ucol] = hi;
                    Ain_lo[urow + i][ucol] = (_Float16)(zh[i] - (float)hi);
                }
                fold[i] = fn; gold[i] = gn;
            }
        } else if (wid == 4) {
            // readout of z_{n-2} via MFMA; zb[(n-1)&1] barrier-separated
            if (n >= 2) {
                const int q = (n - 1) & 1, s = n - 2;
                half8 a0 = *(const half8*)&zb[q][l15][koff];
                half8 a1 = *(const half8*)&zb[q][l15][32 + koff];
                f32x4 racc = (f32x4){rbv, rbv, rbv, rbv};
                racc = MFMA(a0, brd[0], racc);
                racc = MFMA(a1, brd[1], racc);
                if (l15 < 9) {
                    const float tv = tsS[s];
                    #pragma unroll
                    for (int i2 = 0; i2 < 4; ++i2) {
                        const int r = quad * 4 + i2;
                        out[(size_t)(rowbase + r) * (T_STEPS * 9) + s * 9 + ocol]
                            = (l15 < 8) ? racc[i2] : tv;
                    }
                }
            }
        } else if (wid >= 12) {
            if (n < T_STEPS) bias1t[tid - 768] = b0s + tsS[n] * w0s;
        }
        __syncthreads();
    }

    // ---- epilogue: readout of z_255 (stashed in zb[0] at step 256) ----
    if (wid == 4) {
        const int s = T_STEPS - 1;
        half8 a0 = *(const half8*)&zb[0][l15][koff];
        half8 a1 = *(const half8*)&zb[0][l15][32 + koff];
        f32x4 racc = (f32x4){rbv, rbv, rbv, rbv};
        racc = MFMA(a0, brd[0], racc);
        racc = MFMA(a1, brd[1], racc);
        if (l15 < 9) {
            const float tv = tsS[s];
            #pragma unroll
            for (int i2 = 0; i2 < 4; ++i2) {
                const int r = quad * 4 + i2;
                out[(size_t)(rowbase + r) * (T_STEPS * 9) + s * 9 + ocol]
                    = (l15 < 8) ? racc[i2] : tv;
            }
        }
    }
}

extern "C" void kernel_launch(void* const* d_in, const int* in_sizes, int n_in,
                              void* d_out, int out_size, void* d_ws, size_t ws_size,
                              hipStream_t stream) {
    const float* ts  = (const float*)d_in[0];
    const float* dW  = (const float*)d_in[2];
    const float* dW0 = (const float*)d_in[3];
    const float* db0 = (const float*)d_in[4];
    const float* dW1 = (const float*)d_in[5];
    const float* db1 = (const float*)d_in[6];
    const float* dWo = (const float*)d_in[7];
    const float* dbo = (const float*)d_in[8];
    const float* gW0 = (const float*)d_in[9];
    const float* gb0 = (const float*)d_in[10];
    const float* gW1 = (const float*)d_in[11];
    const float* gb1 = (const float*)d_in[12];
    const float* gWo = (const float*)d_in[13];
    const float* gbo = (const float*)d_in[14];
    const float* rW  = (const float*)d_in[15];
    const float* rb  = (const float*)d_in[16];
    float* out = (float*)d_out;

    sde_kernel<<<dim3(BATCH / RPB), dim3(NTH), 0, stream>>>(
        ts, dW, dW0, db0, dW1, db1, dWo, dbo,
        gW0, gb0, gW1, gb1, gWo, gbo, rW, rb, out);
}

// Round 6
// 867.175 us; speedup vs baseline: 1.0007x; 1.0007x over previous
//
#include <hip/hip_runtime.h>
#include <math.h>

#define T_STEPS 256
#define BATCH   4096
#define HID     64
#define MW      128
#define DOUT    8
#define RPB     16    // rows per block -> grid = 256 = 1 block/CU (grid-limited)
#define NTH     1024  // 16 waves -> 4 waves/SIMD; ph1/2: (mlp 2) x (oct 8)
#define AS      72    // Ain/zb row stride in halfs (144B)
#define HS      136   // h1/h2 row stride in halfs (272B)

typedef _Float16 half8 __attribute__((ext_vector_type(8)));
typedef float    f32x4 __attribute__((ext_vector_type(4)));

__device__ __forceinline__ float fast_rcp(float x) { return __builtin_amdgcn_rcpf(x); }
// plain silu: the 0.909 lipswish factor is folded into the NEXT layer's f16 weights
__device__ __forceinline__ float silu(float x) {
    float e = __expf(-x);
    return x * fast_rcp(1.0f + e);
}
__device__ __forceinline__ float fast_tanh(float x) {
    float e = __expf(2.0f * x);
    return 1.0f - 2.0f * fast_rcp(e + 1.0f);
}

#define MFMA(a, b, c) __builtin_amdgcn_mfma_f32_16x16x32_f16((a), (b), (c), 0, 0, 0)

// MFMA 16x16x32 layout (gfx950, guide-verified):
//   A[m][k]: m = lane&15 (batch row), k = (lane>>4)*8 + j
//   B[k][n]: n = lane&15 (out-neuron), k = (lane>>4)*8 + j
//   C/D   : col n = lane&15 (out-neuron), row m = (lane>>4)*4 + reg (batch row)
// Phase 3: the lane producing f,g for (rows quad*4+i, col (wid&3)*16+l15) also
// owns z/zhat for those elements -> update needs no cross-lane/LDS transpose.

// __launch_bounds__(1024, 4): min 4 waves/EU -> VGPR cap 128. R5's (1024,1)
// let the compiler target 64 VGPR and spill the ~110-VGPR state waves to
// scratch (WRITE_SIZE 36.9 -> 86.7 MB). Grid = 1 block/CU, so 128 is free.
__global__ __launch_bounds__(NTH, 4)
void sde_kernel(const float* __restrict__ ts,
                const float* __restrict__ dW,
                const float* __restrict__ dW0, const float* __restrict__ db0,
                const float* __restrict__ dW1, const float* __restrict__ db1,
                const float* __restrict__ dWo, const float* __restrict__ dbo,
                const float* __restrict__ gW0, const float* __restrict__ gb0,
                const float* __restrict__ gW1, const float* __restrict__ gb1,
                const float* __restrict__ gWo, const float* __restrict__ gbo,
                const float* __restrict__ rW,  const float* __restrict__ rb,
                float* __restrict__ out)
{
    __shared__ _Float16 Ain_hi[RPB][AS];   // L1 input (t-folded), hi part
    __shared__ _Float16 Ain_lo[RPB][AS];   // L1 input, lo part (fp32-exact split)
    __shared__ _Float16 h1b[2][RPB][HS];   // layer-1 out per mlp (plain silu)
    __shared__ _Float16 h2b[2][RPB][HS];   // layer-2 out per mlp (plain silu)
    __shared__ _Float16 zb[2][RPB][AS];    // z stash (f16) for MFMA readout
    __shared__ float    bias1t[2 * MW];    // per-step L1 bias incl. t * W0row0
    __shared__ float    tsS[T_STEPS];

    const int tid  = threadIdx.x;
    const int lane = tid & 63;
    const int wid  = tid >> 6;     // 0..15
    const int l15  = lane & 15;
    const int quad = lane >> 4;
    const int mlp  = wid >> 3;     // ph1/2 role: 0 = drift, 1 = diff
    const int oct  = wid & 7;      // 16-col slice of the 128 neurons
    const int cb   = oct * 16;     // col base
    const int rowbase = blockIdx.x * RPB;

    for (int i = tid; i < T_STEPS; i += NTH) tsS[i] = ts[i];

    const float t0   = ts[0];
    const float dt   = ts[1] - t0;
    const float sqdt = sqrtf(dt);

    // ---------------- static weight fragments (B-operand) ----------------
    const float* W0 = mlp ? gW0 : dW0;   // (65,128); row 0 = t weights
    const float* W1 = mlp ? gW1 : dW1;   // (128,128)

    half8 bw1[2], bw2[4];
    #pragma unroll
    for (int kt = 0; kt < 2; ++kt) {
        half8 v;
        #pragma unroll
        for (int j = 0; j < 8; ++j) {
            const int k = kt * 32 + quad * 8 + j;
            v[j] = (_Float16)W0[(1 + k) * MW + cb + l15];
        }
        bw1[kt] = v;
    }
    #pragma unroll
    for (int kt = 0; kt < 4; ++kt) {
        half8 v;
        #pragma unroll
        for (int j = 0; j < 8; ++j) {
            const int k = kt * 32 + quad * 8 + j;
            v[j] = (_Float16)(0.909f * W1[k * MW + cb + l15]);   // 0.909 folded
        }
        bw2[kt] = v;
    }

    const float b2v = (mlp ? gb1 : db1)[cb + l15];

    // ---------------- phase-3 state (waves 0-3) ----------------
    // state wave w owns cols ucol = w*16+l15, rows quad*4+i.
    const int ucol = (wid & 3) * 16 + l15;
    const int urow = quad * 4;

    half8 bw3f[4], bw3g[4];          // 0.909-folded Wo fragments (wid<4 only)
    float b3f = 0.0f, b3g = 0.0f;
    float z[4], zh[4], fold[4], gold[4], dwr[4], dn[4];
    if (wid < 4) {
        #pragma unroll
        for (int kt = 0; kt < 4; ++kt) {
            half8 vf, vg;
            #pragma unroll
            for (int j = 0; j < 8; ++j) {
                const int k = kt * 32 + quad * 8 + j;
                vf[j] = (_Float16)(0.909f * dWo[k * HID + ucol]);
                vg[j] = (_Float16)(0.909f * gWo[k * HID + ucol]);
            }
            bw3f[kt] = vf;
            bw3g[kt] = vg;
        }
        b3f = dbo[ucol];
        b3g = gbo[ucol];
        #pragma unroll
        for (int i = 0; i < 4; ++i) {
            z[i] = 1.0f; zh[i] = 1.0f; dwr[i] = 0.0f;
            dn[i] = dW[(size_t)(rowbase + urow + i) * HID + ucol];   // dW[0]
            Ain_hi[urow + i][ucol] = (_Float16)1.0f;                 // x0 = ones
            Ain_lo[urow + i][ucol] = (_Float16)0.0f;
        }
    }

    // readout fragments (wave 4)
    half8 brd[2];
    float rbv = 0.0f;
    int   ocol = 0;
    if (wid == 4) {
        #pragma unroll
        for (int kt = 0; kt < 2; ++kt) {
            half8 v;
            #pragma unroll
            for (int j = 0; j < 8; ++j) {
                const int k = kt * 32 + quad * 8 + j;
                v[j] = (l15 < 8) ? (_Float16)rW[k * DOUT + l15] : (_Float16)0.0f;
            }
            brd[kt] = v;
        }
        rbv  = (l15 < 8) ? rb[l15] : 0.0f;
        ocol = (l15 == 8) ? 0 : (l15 + 1);
    }

    // t-folded L1 bias owned by waves 12..15 (256 threads cover 2*MW slots)
    float b0s = 0.0f, w0s = 0.0f;
    if (tid >= 768) {
        const int idx = tid - 768;
        b0s = (idx < MW ? db0 : gb0)[idx & (MW - 1)];
        w0s = (idx < MW ? dW0 : gW0)[idx & (MW - 1)];  // W0 row 0
        bias1t[idx] = b0s + t0 * w0s;
    }
    __syncthreads();

    const int koff = quad * 8;

    for (int n = 1; n <= T_STEPS; ++n) {
        // ================= Phase 1: Layer 1, 64 -> 128 (split-A hi/lo) ========
        {
            half8 ah[2], al[2];
            #pragma unroll
            for (int kt = 0; kt < 2; ++kt) {
                ah[kt] = *(const half8*)&Ain_hi[l15][kt * 32 + koff];
                al[kt] = *(const half8*)&Ain_lo[l15][kt * 32 + koff];
            }
            const float b = bias1t[mlp * MW + cb + l15];
            f32x4 acc = (f32x4){b, b, b, b};
            #pragma unroll
            for (int kt = 0; kt < 2; ++kt) {
                acc = MFMA(ah[kt], bw1[kt], acc);
                acc = MFMA(al[kt], bw1[kt], acc);
            }
            #pragma unroll
            for (int i2 = 0; i2 < 4; ++i2)
                h1b[mlp][quad * 4 + i2][cb + l15] = (_Float16)silu(acc[i2]);
        }
        __syncthreads();

        // ================= Phase 2: Layer 2, 128 -> 128 =================
        {
            half8 a[4];
            #pragma unroll
            for (int kt = 0; kt < 4; ++kt)
                a[kt] = *(const half8*)&h1b[mlp][l15][kt * 32 + koff];
            f32x4 acc = (f32x4){b2v, b2v, b2v, b2v};
            #pragma unroll
            for (int kt = 0; kt < 4; ++kt)
                acc = MFMA(a[kt], bw2[kt], acc);
            #pragma unroll
            for (int i2 = 0; i2 < 4; ++i2)
                h2b[mlp][quad * 4 + i2][cb + l15] = (_Float16)silu(acc[i2]);
        }
        __syncthreads();

        // ===== Phase 3: L3 f&g (waves 0-3, in-register update);
        //                readout (wave 4); bias refresh (waves 12-15) =====
        if (wid < 4) {
            half8 a[4];
            #pragma unroll
            for (int kt = 0; kt < 4; ++kt)
                a[kt] = *(const half8*)&h2b[0][l15][kt * 32 + koff];
            f32x4 accF = (f32x4){b3f, b3f, b3f, b3f};
            #pragma unroll
            for (int kt = 0; kt < 4; ++kt)
                accF = MFMA(a[kt], bw3f[kt], accF);
            #pragma unroll
            for (int kt = 0; kt < 4; ++kt)
                a[kt] = *(const half8*)&h2b[1][l15][kt * 32 + koff];
            f32x4 accG = (f32x4){b3g, b3g, b3g, b3g};
            #pragma unroll
            for (int kt = 0; kt < 4; ++kt)
                accG = MFMA(a[kt], bw3g[kt], accG);

            const int p = n & 1;
            const int np = (n < T_STEPS - 2) ? n : (T_STEPS - 2);
            #pragma unroll
            for (int i = 0; i < 4; ++i) {
                const float fn = fast_tanh(accF[i]);
                const float gn = fast_tanh(accG[i]);
                if (n > 1)
                    z[i] += 0.5f * (fold[i] + fn) * dt + 0.5f * (gold[i] + gn) * dwr[i];
                zb[p][urow + i][ucol] = (_Float16)z[i];
                if (n < T_STEPS) {
                    dwr[i] = dn[i] * sqdt;
                    dn[i]  = dW[(size_t)np * (BATCH * HID)
                                + (size_t)(rowbase + urow + i) * HID + ucol];
                    zh[i]  = 2.0f * z[i] - zh[i] + fn * dt + gn * dwr[i];
                    const _Float16 hi = (_Float16)zh[i];
                    Ain_hi[urow + i][ucol] = hi;
                    Ain_lo[urow + i][ucol] = (_Float16)(zh[i] - (float)hi);
                }
                fold[i] = fn; gold[i] = gn;
            }
        } else if (wid == 4) {
            // readout of z_{n-2} via MFMA; zb[(n-1)&1] barrier-separated
            if (n >= 2) {
                const int q = (n - 1) & 1, s = n - 2;
                half8 a0 = *(const half8*)&zb[q][l15][koff];
                half8 a1 = *(const half8*)&zb[q][l15][32 + koff];
                f32x4 racc = (f32x4){rbv, rbv, rbv, rbv};
                racc = MFMA(a0, brd[0], racc);
                racc = MFMA(a1, brd[1], racc);
                if (l15 < 9) {
                    const float tv = tsS[s];
                    #pragma unroll
                    for (int i2 = 0; i2 < 4; ++i2) {
                        const int r = quad * 4 + i2;
                        out[(size_t)(rowbase + r) * (T_STEPS * 9) + s * 9 + ocol]
                            = (l15 < 8) ? racc[i2] : tv;
                    }
                }
            }
        } else if (wid >= 12) {
            if (n < T_STEPS) bias1t[tid - 768] = b0s + tsS[n] * w0s;
        }
        __syncthreads();
    }

    // ---- epilogue: readout of z_255 (stashed in zb[0] at step 256) ----
    if (wid == 4) {
        const int s = T_STEPS - 1;
        half8 a0 = *(const half8*)&zb[0][l15][koff];
        half8 a1 = *(const half8*)&zb[0][l15][32 + koff];
        f32x4 racc = (f32x4){rbv, rbv, rbv, rbv};
        racc = MFMA(a0, brd[0], racc);
        racc = MFMA(a1, brd[1], racc);
        if (l15 < 9) {
            const float tv = tsS[s];
            #pragma unroll
            for (int i2 = 0; i2 < 4; ++i2) {
                const int r = quad * 4 + i2;
                out[(size_t)(rowbase + r) * (T_STEPS * 9) + s * 9 + ocol]
                    = (l15 < 8) ? racc[i2] : tv;
            }
        }
    }
}

extern "C" void kernel_launch(void* const* d_in, const int* in_sizes, int n_in,
                              void* d_out, int out_size, void* d_ws, size_t ws_size,
                              hipStream_t stream) {
    const float* ts  = (const float*)d_in[0];
    const float* dW  = (const float*)d_in[2];
    const float* dW0 = (const float*)d_in[3];
    const float* db0 = (const float*)d_in[4];
    const float* dW1 = (const float*)d_in[5];
    const float* db1 = (const float*)d_in[6];
    const float* dWo = (const float*)d_in[7];
    const float* dbo = (const float*)d_in[8];
    const float* gW0 = (const float*)d_in[9];
    const float* gb0 = (const float*)d_in[10];
    const float* gW1 = (const float*)d_in[11];
    const float* gb1 = (const float*)d_in[12];
    const float* gWo = (const float*)d_in[13];
    const float* gbo = (const float*)d_in[14];
    const float* rW  = (const float*)d_in[15];
    const float* rb  = (const float*)d_in[16];
    float* out = (float*)d_out;

    sde_kernel<<<dim3(BATCH / RPB), dim3(NTH), 0, stream>>>(
        ts, dW, dW0, db0, dW1, db1, dWo, dbo,
        gW0, gb0, gW1, gb1, gWo, gbo, rW, rb, out);
}